// Round 3
// baseline (315.806 us; speedup 1.0000x reference)
//
#include <hip/hip_runtime.h>
#include <hip/hip_bf16.h>
#include <math.h>

// EdgeGAT: B=8, OP=400, MA=200, F_IN=F_OUT=64
// Inputs/output are float32 per the reference; adj is int32.
// z is staged into LDS as bf16 (RNE) to fit 2 blocks/CU; all accumulation f32.
#define B_   8
#define OP_  400
#define MA_  200
#define ZQ   9            // uint4 per LDS z row: 8 data + 1 pad (144 B stride)
#define ZSTR 72           // u16 elements per LDS z row
#define NEGM -1.0e30f     // finite mask sentinel (exp(-1e30 - M) == +0 exactly)

typedef unsigned short u16;
typedef unsigned int   u32;

__device__ __forceinline__ float bf2f(u16 u) {
    union { u32 i; float f; } v; v.i = ((u32)u) << 16; return v.f;
}
// unpack packed 2xbf16 (little-endian: low u16 = element 2k, high = 2k+1)
__device__ __forceinline__ float2 up2(u32 p) {
    union { u32 i; float f; } a, c;
    a.i = p << 16; c.i = p & 0xffff0000u;
    return make_float2(a.f, c.f);
}
__device__ __forceinline__ u16 f2bf(float f) {
    __hip_bfloat16 h = __float2bfloat16(f);   // RNE
    return *(u16*)&h;
}

// ---------------- kernel 1: tiny precompute (all f32) ----------------
// w_e = W_edge @ a_edge ; e_op[b,n] = x[b,n,:].(W_op@a_op) ; e_ma[b,m] = y[b,m,:].(W_ma@a_ma)
__global__ __launch_bounds__(256) void precompute_k(
    const float* __restrict__ x, const float* __restrict__ y,
    const float* __restrict__ Wop, const float* __restrict__ Wma,
    const float* __restrict__ Wedge, const float* __restrict__ att,
    float* __restrict__ ws_we, float* __restrict__ ws_eop, float* __restrict__ ws_ema)
{
    __shared__ float w_s[3 * 64];
    const int tid = threadIdx.x;
    if (tid < 192) {
        const int which = tid >> 6, i = tid & 63;
        const float* W = (which == 0) ? Wop : ((which == 1) ? Wma : Wedge);
        const float* a = att + which * 64;
        float acc = 0.f;
        #pragma unroll 8
        for (int f = 0; f < 64; ++f) acc = fmaf(W[i * 64 + f], a[f], acc);
        w_s[tid] = acc;
    }
    __syncthreads();
    if (blockIdx.x == 0 && tid < 64) ws_we[tid] = w_s[128 + tid];

    const int g = blockIdx.x * 256 + tid;
    if (g < B_ * OP_) {
        const float4* row = (const float4*)(x + (size_t)g * 64);
        float acc = 0.f;
        #pragma unroll
        for (int j = 0; j < 16; ++j) {
            float4 q = row[j];
            acc += q.x * w_s[4*j+0] + q.y * w_s[4*j+1]
                 + q.z * w_s[4*j+2] + q.w * w_s[4*j+3];
        }
        ws_eop[g] = acc;
    } else if (g < B_ * OP_ + B_ * MA_) {
        const int h = g - B_ * OP_;
        const float4* row = (const float4*)(y + (size_t)h * 64);
        float acc = 0.f;
        #pragma unroll
        for (int j = 0; j < 16; ++j) {
            float4 q = row[j];
            acc += q.x * w_s[64+4*j+0] + q.y * w_s[64+4*j+1]
                 + q.z * w_s[64+4*j+2] + q.w * w_s[64+4*j+3];
        }
        ws_ema[h] = acc;
    }
}

// ---------------- kernel 2: one block per (b, m) output row ----------------
__global__ __launch_bounds__(256) void gat_main(
    const float* __restrict__ x, const float* __restrict__ y,
    const float* __restrict__ z, const int* __restrict__ adj,
    const float* __restrict__ Wop, const float* __restrict__ Wma,
    const float* __restrict__ Wedge,
    const float* __restrict__ ws_we, const float* __restrict__ ws_eop,
    const float* __restrict__ ws_ema, float* __restrict__ out)
{
    __shared__ uint4  z4[OP_ * ZQ];     // 57600 B, 16B-aligned; z slice as bf16
    __shared__ float s_arr[OP_];        // scores -> att
    __shared__ float we_s[64];
    __shared__ float y_s[64];
    __shared__ float red[8];
    __shared__ float vred[4][64];
    __shared__ float ured[4][64];

    u16*   const z_s = (u16*)z4;
    uint2* const z2  = (uint2*)z4;

    const int tid = threadIdx.x;
    const int wv = tid >> 6, ln = tid & 63;
    const int bm = blockIdx.x;
    const int b = bm / MA_, m = bm % MA_;

    // ---- stage: z[b, n, m, 0:64] (f32) -> LDS bf16, single HBM read of z ----
    const float* zb = z + ((size_t)b * OP_ * MA_ + m) * 64;
    for (int c = tid; c < OP_ * 16; c += 256) {
        const int n = c >> 4, j = c & 15;
        float4 q = *(const float4*)(zb + (size_t)n * (MA_ * 64) + j * 4);
        u32 lo = ((u32)f2bf(q.y) << 16) | f2bf(q.x);
        u32 hi = ((u32)f2bf(q.w) << 16) | f2bf(q.z);
        z2[n * 18 + j] = make_uint2(lo, hi);      // 8B store, 8B-aligned
    }
    if (tid < 64)       we_s[tid]      = ws_we[tid];
    else if (tid < 128) y_s[tid - 64]  = y[((size_t)b * MA_ + m) * 64 + (tid - 64)];
    __syncthreads();

    // ---- phase A: s[n] = mask(leaky_relu(z_row.w_e + e_op[n] + e_ma)) ----
    const float ema = ws_ema[b * MA_ + m];
    for (int n = tid; n < OP_; n += 256) {
        const uint4* zr = &z4[n * ZQ];
        float acc = 0.f;
        #pragma unroll
        for (int j = 0; j < 8; ++j) {
            uint4 q = zr[j];
            float2 p0 = up2(q.x), p1 = up2(q.y), p2 = up2(q.z), p3 = up2(q.w);
            acc += p0.x * we_s[8*j+0] + p0.y * we_s[8*j+1]
                 + p1.x * we_s[8*j+2] + p1.y * we_s[8*j+3]
                 + p2.x * we_s[8*j+4] + p2.y * we_s[8*j+5]
                 + p3.x * we_s[8*j+6] + p3.y * we_s[8*j+7];
        }
        float e = acc + ws_eop[b * OP_ + n] + ema;
        e = (e >= 0.f) ? e : 0.01f * e;                        // leaky_relu(0.01)
        const int ad = adj[((size_t)(b * OP_ + n)) * MA_ + m]; // adjT[b,m,n]
        s_arr[n] = (ad != 0) ? e : NEGM;                       // finite sentinel
    }
    __syncthreads();

    // ---- phase B: softmax over n (finite-math-safe) ----
    float lm = NEGM;
    for (int n = tid; n < OP_; n += 256) lm = fmaxf(lm, s_arr[n]);
    #pragma unroll
    for (int o = 32; o > 0; o >>= 1) lm = fmaxf(lm, __shfl_xor(lm, o, 64));
    if (ln == 0) red[wv] = lm;
    __syncthreads();
    const float M = fmaxf(fmaxf(red[0], red[1]), fmaxf(red[2], red[3]));
    const bool empty = (M < -1.0e29f);                         // all-masked row
    float ls = 0.f;
    for (int n = tid; n < OP_; n += 256) {
        float p = __expf(s_arr[n] - M);   // masked: exp(-1e30 - M) == +0 exactly
        if (empty) p = 0.f;
        s_arr[n] = p;
        ls += p;
    }
    #pragma unroll
    for (int o = 32; o > 0; o >>= 1) ls += __shfl_xor(ls, o, 64);
    if (ln == 0) red[4 + wv] = ls;
    __syncthreads();
    const float L = red[4] + red[5] + red[6] + red[7];
    const float inv = (L > 0.f) ? (1.f / L) : 0.f;
    for (int n = tid; n < OP_; n += 256) s_arr[n] *= inv;
    __syncthreads();

    // ---- phase C: v = sum_n att*z_row (LDS bf16), u = sum_n att*x (f32, L2) ----
    const float* xb = x + (size_t)b * OP_ * 64;
    float v = 0.f, u = 0.f;
    for (int n = wv; n < OP_; n += 4) {
        const float a = s_arr[n];                  // wave-uniform LDS broadcast
        if (a > 0.f) {                             // uniform branch; ~50% masked
            v = fmaf(a, bf2f(z_s[n * ZSTR + ln]), v);
            u = fmaf(a, xb[(size_t)n * 64 + ln], u);
        }
    }
    vred[wv][ln] = v; ured[wv][ln] = u;
    __syncthreads();

    // ---- epilogue (wave 0): h' = v@W_edge + u@W_op + y@W_ma ; elu ----
    if (tid < 64) {
        const int f = tid;
        float hv = 0.f;
        #pragma unroll 8
        for (int i = 0; i < 64; ++i) {
            const float vi = vred[0][i] + vred[1][i] + vred[2][i] + vred[3][i];
            const float ui = ured[0][i] + ured[1][i] + ured[2][i] + ured[3][i];
            hv += vi * Wedge[i * 64 + f]
                + ui * Wop[i * 64 + f]
                + y_s[i] * Wma[i * 64 + f];
        }
        float o;
        if (hv > 0.f) o = hv;
        else          o = __expf(hv) - 1.f;        // elu
        out[((size_t)b * MA_ + m) * 64 + f] = o;
    }
}

extern "C" void kernel_launch(void* const* d_in, const int* in_sizes, int n_in,
                              void* d_out, int out_size, void* d_ws, size_t ws_size,
                              hipStream_t stream) {
    const float* x     = (const float*)d_in[0];
    const float* y     = (const float*)d_in[1];
    const float* z     = (const float*)d_in[2];
    const int*   adj   = (const int*)d_in[3];
    const float* Wop   = (const float*)d_in[4];
    const float* Wma   = (const float*)d_in[5];
    const float* Wedge = (const float*)d_in[6];
    const float* att   = (const float*)d_in[7];

    float* ws     = (float*)d_ws;
    float* ws_we  = ws;                       // 64
    float* ws_eop = ws + 64;                  // B*OP = 3200
    float* ws_ema = ws + 64 + B_ * OP_;       // B*MA = 1600

    precompute_k<<<(B_ * OP_ + B_ * MA_ + 255) / 256, 256, 0, stream>>>(
        x, y, Wop, Wma, Wedge, att, ws_we, ws_eop, ws_ema);
    gat_main<<<B_ * MA_, 256, 0, stream>>>(
        x, y, z, adj, Wop, Wma, Wedge, ws_we, ws_eop, ws_ema, (float*)d_out);
}

// Round 4
// 271.908 us; speedup vs baseline: 1.1614x; 1.1614x over previous
//
#include <hip/hip_runtime.h>
#include <math.h>

// EdgeGAT: B=8, OP=400, MA=200, F=64. f32 in/out, adj int32.
// Flash-style split over n: 4 chunks x 100 rows, z rows register-resident.
#define B_   8
#define OP_  400
#define MA_  200
#define NCH  4            // n-chunks per (b,m) row
#define CH   100          // rows per chunk
#define RPW  25           // rows per wave (CH / 4 waves)
#define PSTR 132          // partial stride: v[64] u[64] M L (+2 pad)
#define NEGM -1.0e30f     // finite mask sentinel

// ---------------- kernel 1: precompute (wave-per-row) ----------------
// w_e = W_edge@a_edge ; e_op[b,n] = x[b,n,:].(W_op@a_op) ; e_ma[b,m] = y[b,m,:].(W_ma@a_ma)
__global__ __launch_bounds__(256) void precompute_k(
    const float* __restrict__ x, const float* __restrict__ y,
    const float* __restrict__ Wop, const float* __restrict__ Wma,
    const float* __restrict__ Wedge, const float* __restrict__ att,
    float* __restrict__ ws_we, float* __restrict__ ws_eop, float* __restrict__ ws_ema)
{
    __shared__ float w_s[192];
    const int tid = threadIdx.x, wv = tid >> 6, ln = tid & 63;
    if (tid < 192) {
        const int which = tid >> 6, i = tid & 63;
        const float* W = (which == 0) ? Wop : ((which == 1) ? Wma : Wedge);
        const float* a = att + which * 64;
        float acc = 0.f;
        #pragma unroll 8
        for (int f = 0; f < 64; ++f) acc = fmaf(W[i * 64 + f], a[f], acc);
        w_s[tid] = acc;
    }
    __syncthreads();
    if (blockIdx.x == 0 && tid < 64) ws_we[tid] = w_s[128 + tid];

    const int row = blockIdx.x * 4 + wv;           // 0 .. 4799
    if (row < B_ * OP_) {
        float s = x[(size_t)row * 64 + ln] * w_s[ln];
        #pragma unroll
        for (int o = 32; o > 0; o >>= 1) s += __shfl_xor(s, o, 64);
        if (ln == 0) ws_eop[row] = s;
    } else if (row < B_ * OP_ + B_ * MA_) {
        const int r2 = row - B_ * OP_;
        float s = y[(size_t)r2 * 64 + ln] * w_s[64 + ln];
        #pragma unroll
        for (int o = 32; o > 0; o >>= 1) s += __shfl_xor(s, o, 64);
        if (ln == 0) ws_ema[r2] = s;
    }
}

// ---------------- kernel 2: chunk partials (block = (b,m,chunk)) ----------------
__global__ __launch_bounds__(256) void gat_chunk(
    const float* __restrict__ x, const float* __restrict__ z,
    const int* __restrict__ adj,
    const float* __restrict__ ws_we, const float* __restrict__ ws_eop,
    const float* __restrict__ ws_ema, float* __restrict__ part)
{
    __shared__ float we_s[64];
    __shared__ float s_arr[CH];
    __shared__ float red[8];
    __shared__ float vred[4][64];
    __shared__ float ured[4][64];

    const int tid = threadIdx.x, wv = tid >> 6, ln = tid & 63;
    const int blk = blockIdx.x;                 // bm * NCH + c
    const int bm = blk / NCH, c = blk % NCH;
    const int b = bm / MA_, m = bm % MA_;
    const int n0 = c * CH;
    const int nbase = wv * RPW;                 // this wave's rows within chunk

    if (tid < 64) we_s[tid] = ws_we[tid];
    __syncthreads();

    // ---- load this wave's 25 z rows into registers (coalesced 256B rows) ----
    const float* zb = z + ((size_t)(b * OP_ + n0) * MA_ + m) * 64;
    float zreg[RPW];
    #pragma unroll
    for (int i = 0; i < RPW; ++i)
        zreg[i] = zb[(size_t)(nbase + i) * (MA_ * 64) + ln];

    // ---- raw scores: dot(z_row, w_e) via shuffle reduce ----
    #pragma unroll
    for (int i = 0; i < RPW; ++i) {
        float s = zreg[i] * we_s[ln];
        #pragma unroll
        for (int o = 32; o > 0; o >>= 1) s += __shfl_xor(s, o, 64);
        if (ln == 0) s_arr[nbase + i] = s;
    }
    __syncthreads();

    // ---- mask + leaky_relu + e-terms (threads 0..CH-1) ----
    const float ema = ws_ema[bm];
    if (tid < CH) {
        const int n = n0 + tid;
        float e = s_arr[tid] + ws_eop[b * OP_ + n] + ema;
        e = (e >= 0.f) ? e : 0.01f * e;
        const int ad = adj[((size_t)(b * OP_ + n)) * MA_ + m];
        s_arr[tid] = (ad != 0) ? e : NEGM;
    }
    __syncthreads();

    // ---- chunk max ----
    float lm = NEGM;
    for (int n = tid; n < CH; n += 256) lm = fmaxf(lm, s_arr[n]);
    #pragma unroll
    for (int o = 32; o > 0; o >>= 1) lm = fmaxf(lm, __shfl_xor(lm, o, 64));
    if (ln == 0) red[wv] = lm;
    __syncthreads();
    const float M = fmaxf(fmaxf(red[0], red[1]), fmaxf(red[2], red[3]));

    // ---- p = exp(s - M) (0 for masked / empty chunk), partial sum L ----
    float ls = 0.f;
    for (int n = tid; n < CH; n += 256) {
        const float sv = s_arr[n];
        const float p = (sv > -1.0e29f) ? __expf(sv - M) : 0.f;
        s_arr[n] = p;
        ls += p;
    }
    #pragma unroll
    for (int o = 32; o > 0; o >>= 1) ls += __shfl_xor(ls, o, 64);
    if (ln == 0) red[4 + wv] = ls;
    __syncthreads();
    const float L = red[4] + red[5] + red[6] + red[7];

    // ---- v = sum p*z (registers), u = sum p*x (L2-resident reads) ----
    const float* xb = x + (size_t)(b * OP_ + n0) * 64;
    float v = 0.f, u = 0.f;
    #pragma unroll
    for (int i = 0; i < RPW; ++i) {
        const float p = s_arr[nbase + i];
        v = fmaf(p, zreg[i], v);
        u = fmaf(p, xb[(size_t)(nbase + i) * 64 + ln], u);
    }
    vred[wv][ln] = v; ured[wv][ln] = u;
    __syncthreads();

    // ---- write partial: v[64] u[64] M L ----
    float* pp = part + (size_t)blk * PSTR;
    if (tid < 64)        pp[tid]      = vred[0][tid] + vred[1][tid] + vred[2][tid] + vred[3][tid];
    else if (tid < 128)  pp[tid]      = ured[0][tid-64] + ured[1][tid-64] + ured[2][tid-64] + ured[3][tid-64];
    else if (tid == 128) { pp[128] = M; pp[129] = L; }
}

// ---------------- kernel 3: combine + epilogue (wave per (b,m) row) ----------------
__global__ __launch_bounds__(256) void gat_combine(
    const float* __restrict__ y,
    const float* __restrict__ Wop, const float* __restrict__ Wma,
    const float* __restrict__ Wedge,
    const float* __restrict__ part, float* __restrict__ out)
{
    __shared__ float vs[4][64], us[4][64], ys[4][64];
    const int tid = threadIdx.x, wv = tid >> 6, ln = tid & 63;
    const int row = blockIdx.x * 4 + wv;        // bm, grid covers 1600 exactly

    const float* pp = part + (size_t)row * NCH * PSTR;
    float M = NEGM;
    #pragma unroll
    for (int c = 0; c < NCH; ++c) M = fmaxf(M, pp[c * PSTR + 128]);
    float L = 0.f, v = 0.f, u = 0.f;
    #pragma unroll
    for (int c = 0; c < NCH; ++c) {
        const float Mc = pp[c * PSTR + 128];
        const float w  = (Mc > -1.0e29f) ? __expf(Mc - M) : 0.f;
        L += w * pp[c * PSTR + 129];
        v += w * pp[c * PSTR + ln];
        u += w * pp[c * PSTR + 64 + ln];
    }
    const float inv = (L > 0.f) ? (1.f / L) : 0.f;
    vs[wv][ln] = v * inv;
    us[wv][ln] = u * inv;
    ys[wv][ln] = y[(size_t)row * 64 + ln];
    // same-wave LDS write->read: no barrier needed (compiler emits lgkmcnt)
    __syncthreads();

    float hv = 0.f;
    #pragma unroll 8
    for (int i = 0; i < 64; ++i) {
        hv += vs[wv][i] * Wedge[i * 64 + ln]
            + us[wv][i] * Wop[i * 64 + ln]
            + ys[wv][i] * Wma[i * 64 + ln];
    }
    out[(size_t)row * 64 + ln] = (hv > 0.f) ? hv : (__expf(hv) - 1.f);
}

extern "C" void kernel_launch(void* const* d_in, const int* in_sizes, int n_in,
                              void* d_out, int out_size, void* d_ws, size_t ws_size,
                              hipStream_t stream) {
    const float* x     = (const float*)d_in[0];
    const float* y     = (const float*)d_in[1];
    const float* z     = (const float*)d_in[2];
    const int*   adj   = (const int*)d_in[3];
    const float* Wop   = (const float*)d_in[4];
    const float* Wma   = (const float*)d_in[5];
    const float* Wedge = (const float*)d_in[6];
    const float* att   = (const float*)d_in[7];

    float* ws     = (float*)d_ws;
    float* ws_we  = ws;                              // 64
    float* ws_eop = ws + 64;                         // B*OP = 3200
    float* ws_ema = ws + 64 + B_ * OP_;              // B*MA = 1600
    float* part   = ws + 64 + B_ * OP_ + B_ * MA_;   // 6400 * 132 = 844800

    precompute_k<<<1200, 256, 0, stream>>>(
        x, y, Wop, Wma, Wedge, att, ws_we, ws_eop, ws_ema);
    gat_chunk<<<B_ * MA_ * NCH, 256, 0, stream>>>(
        x, z, adj, ws_we, ws_eop, ws_ema, part);
    gat_combine<<<(B_ * MA_) / 4, 256, 0, stream>>>(
        y, Wop, Wma, Wedge, part, (float*)d_out);
}